// Round 1
// baseline (208.590 us; speedup 1.0000x reference)
//
#include <hip/hip_runtime.h>

typedef short short8 __attribute__((ext_vector_type(8)));
typedef float float4v __attribute__((ext_vector_type(4)));
typedef int int4v __attribute__((ext_vector_type(4)));
typedef unsigned int uint2v __attribute__((ext_vector_type(2)));
typedef unsigned short ushort_t;

#define INV_EXT (1.0f / 0.048f)
#define HN 32
#define KK 15
#define CIN 64
#define COUT 64
#define PB 16      /* points per block */
#define JH 512     /* j-slots per ct-half (2 of 4 ct groups) */
#define NSLOT 16   /* stats atomic slots */

// round-half-up bf16
__device__ inline ushort_t rh_bf16(float f) {
    return (ushort_t)((__float_as_uint(f) + 0x8000u) >> 16);
}
// pack two floats into two bf16 in one u32 (lo = a, hi = b)
__device__ inline unsigned pk_bf16(float a, float b) {
    unsigned ua = __float_as_uint(a) + 0x8000u;
    unsigned ub = __float_as_uint(b) + 0x8000u;
    return (ua >> 16) | (ub & 0xffff0000u);
}

union Frag8 { short8 s; unsigned u[4]; };

// wtS element index within half-tile: row p (1 KB = 512 shorts), local j (0..511).
// 16B-granule XOR swizzle by p so phase-3 reads (p = lane&15) spread banks.
__device__ inline int wtJh(int p, int j) {
    return p * JH + ((((j >> 3) ^ (p & 7)) << 3) | (j & 7));
}

// ================= K1: main KPConv (ct-split, 18 KB LDS, 8 blocks/CU) =========
// LDS budget: wtS 16 KB + indS 2 KB = 18 KB -> 8 blocks/CU = 32 waves (100% occ).
// Neighbor coords are embedded in wtS rows during phases 0-1 (each point's own
// 1 KB row; overwritten by the owning wave in phase 2 only after consumption).
template <bool XB>
__global__ __launch_bounds__(256, 8)
void kpconv_main(const float* __restrict__ q_pts,
                 const float* __restrict__ s_pts,
                 const int*   __restrict__ inds,
                 const float* __restrict__ x,
                 const float* __restrict__ kpts,
                 const ushort_t* __restrict__ W3,   // [128 kd-octets][64 d][8] bf16
                 const unsigned* __restrict__ xb,   // [N][2 half][16 dwords]
                 float* __restrict__ out,
                 float* __restrict__ sums, int N)
{
    __shared__ __align__(16) short wtS[PB * JH];   // 16 KB
    __shared__ int indS[PB * HN];                  // 2 KB

    const int t = threadIdx.x;
    const int n0 = blockIdx.x * PB;
    const int lane = t & 63;
    const int wid = t >> 6;
    const int l15 = lane & 15;
    const int q = lane >> 4;

    float* fp = (float*)wtS;   // coord region: fp[p*256 + c*32 + h], 384 B of 1 KB row

    // ---- phase 0: gather RAW neighbor coords + indices (q subtracted in ph1) ----
    for (int it = 0; it < 2; ++it) {
        int pi = t + it * 256;          // (p,h)
        int p = pi >> 5, h = pi & 31;
        int n = n0 + p;
        float sx = 1e9f, sy = 1e9f, sz = 1e9f; int idx = 0;
        if (n < N) {
            idx = inds[n * HN + h];
            const float* sp = s_pts + (size_t)idx * 3;
            sx = sp[0]; sy = sp[1]; sz = sp[2];
        }
        indS[pi] = idx;
        fp[p * 256 + h]      = sx;
        fp[p * 256 + 32 + h] = sy;
        fp[p * 256 + 64 + h] = sz;
    }
    __syncthreads();

    // ---- phase 1: influence weights into A-fragments (A[m=k'=l15][k=h=q*8+j]) ----
    int kidx = l15 < KK ? l15 : 0;
    float kx = kpts[kidx * 3 + 0];
    float ky = kpts[kidx * 3 + 1];
    float kz = kpts[kidx * 3 + 2];
    if (l15 >= KK) { kx = 3e4f; ky = 3e4f; kz = 3e4f; }  // pad kp -> w = 0
    Frag8 afrag[4];
#pragma unroll
    for (int i = 0; i < 4; ++i) {
        int p = wid * 4 + i;
        int n = n0 + p;
        int nc = n < N ? n : 0;
        float qkx = q_pts[nc * 3 + 0] + kx;   // s - (q+kp): err ~6e-8 << d
        float qky = q_pts[nc * 3 + 1] + ky;
        float qkz = q_pts[nc * 3 + 2] + kz;
        int base = p * 256 + q * 8;
        float4v x0 = *(float4v*)&fp[base],      x1 = *(float4v*)&fp[base + 4];
        float4v y0 = *(float4v*)&fp[base + 32], y1 = *(float4v*)&fp[base + 36];
        float4v z0 = *(float4v*)&fp[base + 64], z1 = *(float4v*)&fp[base + 68];
        float w[8];
#pragma unroll
        for (int j = 0; j < 8; ++j) {
            float dx = (j < 4 ? x0[j & 3] : x1[j & 3]) - qkx;
            float dy = (j < 4 ? y0[j & 3] : y1[j & 3]) - qky;
            float dz = (j < 4 ? z0[j & 3] : z1[j & 3]) - qkz;
            float d = __builtin_amdgcn_sqrtf(fmaf(dx, dx, fmaf(dy, dy, dz * dz)));
            w[j] = fmaxf(fmaf(d, -INV_EXT, 1.0f), 0.0f);
        }
#pragma unroll
        for (int jj = 0; jj < 4; ++jj)
            afrag[i].u[jj] = pk_bf16(w[2 * jj], w[2 * jj + 1]);
    }
    // NOTE: no barrier needed here — each wave reads only its own rows above and
    // writes only its own rows below; cross-wave data was fenced after phase 0.

    // ---- phases 2+3, ct-split into two halves; acc3 carried across halves ----
    const int d0 = wid * 16;
    float4v acc3 = {0.f, 0.f, 0.f, 0.f};
    const ushort_t* wb = W3 + (size_t)q * 512 + (d0 + l15) * 8;

#pragma unroll
    for (int hf = 0; hf < 2; ++hf) {
        // -- phase 2 (half): wt[k'][c] for ct = 2hf, 2hf+1 --
#pragma unroll
        for (int i = 0; i < 4; ++i) {
            int p = wid * 4 + i;
            int ibase = p * HN + q * 8;
            int4v ia = *(int4v*)&indS[ibase];       // broadcast b128
            int4v ib = *(int4v*)&indS[ibase + 4];
            unsigned D[8];
            const float* rpf[8];
            if constexpr (XB) {
#pragma unroll
                for (int j = 0; j < 8; ++j) {
                    int idx = j < 4 ? ia[j] : ib[j - 4];
                    D[j] = xb[(size_t)idx * 32 + hf * 16 + l15];
                }
            } else {
#pragma unroll
                for (int j = 0; j < 8; ++j) {
                    int idx = j < 4 ? ia[j] : ib[j - 4];
                    rpf[j] = x + (size_t)idx * CIN;
                }
            }
#pragma unroll
            for (int cth = 0; cth < 2; ++cth) {
                int ct = 2 * hf + cth;
                Frag8 b;
                if constexpr (XB) {
#pragma unroll
                    for (int jj = 0; jj < 4; ++jj) {
                        unsigned lo = D[2 * jj], hi = D[2 * jj + 1];
                        b.u[jj] = cth == 0 ? ((lo & 0xffffu) | (hi << 16))
                                           : ((lo >> 16) | (hi & 0xffff0000u));
                    }
                } else {
#pragma unroll
                    for (int jj = 0; jj < 4; ++jj) {
                        unsigned lo = rh_bf16(rpf[2 * jj][ct * 16 + l15]);
                        unsigned hi = rh_bf16(rpf[2 * jj + 1][ct * 16 + l15]);
                        b.u[jj] = lo | (hi << 16);
                    }
                }
                float4v acc = {0.f, 0.f, 0.f, 0.f};
                acc = __builtin_amdgcn_mfma_f32_16x16x32_bf16(afrag[i].s, b.s, acc, 0, 0, 0);
                // D row m = k' = q*4+r, col n = c = ct*16+l15.
                // kd-slot j = quad*4 + r, quad = l15 + 16*(q^ct) + 64*ct
                uint2v v2;
                v2[0] = pk_bf16(acc[0], acc[1]);
                v2[1] = pk_bf16(acc[2], acc[3]);
                int quad = l15 + 16 * (q ^ ct) + 64 * ct;
                int jloc = quad * 4 - hf * JH;       // [0, 512)
                *(uint2v*)&wtS[wtJh(p, jloc)] = v2;
            }
        }
        __syncthreads();

        // -- phase 3 (half): OUT[16p x 64d] += wt-half @ W3-half --
        const ushort_t* wbh = wb + (size_t)hf * (64 * 512);
#pragma unroll 8
        for (int s = 0; s < 16; ++s) {
            short8 a = *(short8*)&wtS[wtJh(l15, s * 32 + q * 8)];
            short8 bb = *(const short8*)(wbh + (size_t)s * 2048);
            acc3 = __builtin_amdgcn_mfma_f32_16x16x32_bf16(a, bb, acc3, 0, 0, 0);
        }
        if (hf == 0) __syncthreads();   // all reads done before ph2b overwrites wtS
    }

    // ---- epilogue: store + fused per-channel stats (slotted atomics) ----
    {
        float s1 = 0.f, s2 = 0.f;
#pragma unroll
        for (int r = 0; r < 4; ++r) {
            int p = q * 4 + r;
            int n = n0 + p;
            float v = acc3[r];
            if (n < N) { out[n * COUT + d0 + l15] = v; s1 += v; s2 += v * v; }
        }
        s1 += __shfl_xor(s1, 16); s2 += __shfl_xor(s2, 16);
        s1 += __shfl_xor(s1, 32); s2 += __shfl_xor(s2, 32);
        if (q == 0) {
            int slot = blockIdx.x & (NSLOT - 1);
            atomicAdd(&sums[slot * 128 + d0 + l15], s1);
            atomicAdd(&sums[slot * 128 + 64 + d0 + l15], s2);
        }
    }
}

// ================= K0: prep (zero stats, W->W3 blocked layout, x->xb split) ===
template <bool XB>
__global__ void prep_kernel(const float* __restrict__ W, const float* __restrict__ x,
                            float* sums, ushort_t* W3, unsigned* xb, int N)
{
    long gt = (long)blockIdx.x * 256 + threadIdx.x;
    long stride = (long)gridDim.x * 256;
    if (gt < NSLOT * 128) sums[gt] = 0.f;
    for (long i = gt; i < COUT * 1024; i += stride) {
        int d = (int)((i >> 3) & 63);
        int j = (int)(((i >> 9) << 3) | (i & 7));  // kd-slot
        int quad = j >> 2, r = j & 3;
        int l15 = quad & 15, e = (quad >> 4) & 3, ct = quad >> 6;
        int k = (e ^ ct) * 4 + r, c = ct * 16 + l15;
        W3[i] = (k < KK) ? rh_bf16(W[(k * CIN + c) * COUT + d]) : (ushort_t)0;
    }
    if constexpr (XB) {
        // xb[n][hf][tt] = pk(bf16 x[n][hf*32+tt], bf16 x[n][hf*32+16+tt])
        // lane tt at half hf gets c = 2hf*16+tt (lo) and (2hf+1)*16+tt (hi)
        long nq = (long)N * 16;
        for (long iq = gt; iq < nq; iq += stride) {
            long n = iq >> 4; int tt = (int)(iq & 15);
            const float* xp = x + n * 64;
            unsigned* xq = xb + n * 32;
            xq[tt]      = pk_bf16(xp[tt],      xp[tt + 16]);
            xq[16 + tt] = pk_bf16(xp[tt + 32], xp[tt + 48]);
        }
    }
}

// ================= K2: reduce slots + instance-norm + LeakyReLU ========
__global__ void norm_kernel(float* out, const float* __restrict__ sums, int N)
{
    __shared__ float meanS[64], invS[64];
    int t = threadIdx.x;
    if (t < 64) {
        float s1 = 0.f, s2 = 0.f;
#pragma unroll
        for (int sl = 0; sl < NSLOT; ++sl) {
            s1 += sums[sl * 128 + t];
            s2 += sums[sl * 128 + 64 + t];
        }
        float invN = 1.0f / (float)N;
        float mean = s1 * invN;
        float var = fmaxf(s2 * invN - mean * mean, 0.f);
        meanS[t] = mean;
        invS[t] = rsqrtf(var + 1e-5f);
    }
    __syncthreads();
    long total = (long)N * 64 / 4;
    for (long i = (long)blockIdx.x * blockDim.x + t; i < total;
         i += (long)gridDim.x * blockDim.x) {
        int cb = (int)((i * 4) & 63);
        float4v v = *(float4v*)&out[i * 4];
#pragma unroll
        for (int j = 0; j < 4; ++j) {
            float val = (v[j] - meanS[cb + j]) * invS[cb + j];
            v[j] = val >= 0.f ? val : 0.1f * val;
        }
        *(float4v*)&out[i * 4] = v;
    }
}

extern "C" void kernel_launch(void* const* d_in, const int* in_sizes, int n_in,
                              void* d_out, int out_size, void* d_ws, size_t ws_size,
                              hipStream_t stream)
{
    const float* q  = (const float*)d_in[0];
    const float* s  = (const float*)d_in[1];
    const int* inds = (const int*)d_in[2];
    const float* x  = (const float*)d_in[3];
    const float* kp = (const float*)d_in[4];
    const float* W  = (const float*)d_in[5];
    float* out = (float*)d_out;
    int N = in_sizes[0] / 3;

    float* sums  = (float*)d_ws;                                // 8 KB
    ushort_t* W3 = (ushort_t*)((char*)d_ws + 8192);             // 128 KB
    unsigned* xb = (unsigned*)((char*)d_ws + 8192 + 131072);    // N*128 B
    bool useXB = ws_size >= 8192 + 131072 + (size_t)N * CIN * 2;

    int nblk = (N + PB - 1) / PB;
    if (useXB) {
        prep_kernel<true ><<<1024, 256, 0, stream>>>(W, x, sums, W3, xb, N);
        kpconv_main<true ><<<nblk, 256, 0, stream>>>(q, s, inds, x, kp, W3, xb, out, sums, N);
    } else {
        prep_kernel<false><<<1024, 256, 0, stream>>>(W, x, sums, W3, xb, N);
        kpconv_main<false><<<nblk, 256, 0, stream>>>(q, s, inds, x, kp, W3, xb, out, sums, N);
    }
    norm_kernel<<<2048, 256, 0, stream>>>(out, sums, N);
}